// Round 8
// baseline (272.178 us; speedup 1.0000x reference)
//
#include <hip/hip_runtime.h>

#define N_NODES 100000
#define NPAD    100352          // padded row count for A (784*128)
#define DIM     128
#define K2      256             // concatenated K ([mean | x])
#define SCAN_B  1024
#define NSCANB  ((N_NODES + SCAN_B - 1) / SCAN_B)   // 98
#define CONVB   6250            // convert blocks: N*16/256
#define WBB     16              // wb_build blocks
#define NSHARD  8
#define SHROWS  ((N_NODES + NSHARD - 1) / NSHARD)   // 12500
#define BPS     128             // fill blocks per shard
#define GEMMROWS 128            // rows per GEMM block (4 waves x 32 rows)

typedef __attribute__((ext_vector_type(8))) short bf16x8;
typedef __attribute__((ext_vector_type(4))) float f32x4;

__device__ __forceinline__ void atomAddF(float* p, float v) { unsafeAtomicAdd(p, v); }

__device__ __forceinline__ float bf2f(unsigned short u) {
    union { unsigned u; float f; } c; c.u = ((unsigned)u) << 16; return c.f;
}
__device__ __forceinline__ unsigned short f2bf(float f) {
    union { float f; unsigned u; } c; c.f = f;
    unsigned r = (c.u + 0x7FFF + ((c.u >> 16) & 1)) >> 16;   // RNE
    return (unsigned short)r;
}
__device__ __forceinline__ unsigned packbf(float a, float b) {
    return (unsigned)f2bf(a) | ((unsigned)f2bf(b) << 16);
}

// ---------------------------------------------------------------------------
// Phase 1 (merged): hist(dst) | x->bf16 into axk[:,128:256] | W->bf16 frag order
// ---------------------------------------------------------------------------
__global__ __launch_bounds__(256) void phase1_kernel(
    const float* __restrict__ x, const int* __restrict__ ei,
    const float* __restrict__ Wl, const float* __restrict__ Wr,
    unsigned short* __restrict__ axk, unsigned short* __restrict__ wb,
    int* __restrict__ counts, int E, int HB)
{
    int b = blockIdx.x;
    if (b < HB) {                              // ---- histogram of dst
        int e = b * 256 + threadIdx.x;
        if (e < E) atomicAdd(&counts[ei[E + e]], 1);
    } else if (b < HB + CONVB) {               // ---- x -> bf16
        int i = (b - HB) * 256 + threadIdx.x;  // one thread per 8 floats
        int n = i >> 4, c8 = (i & 15) << 3;
        const float4* xp = reinterpret_cast<const float4*>(x + (size_t)n * DIM + c8);
        float4 v0 = xp[0], v1 = xp[1];
        uint4 o;
        o.x = packbf(v0.x, v0.y); o.y = packbf(v0.z, v0.w);
        o.z = packbf(v1.x, v1.y); o.w = packbf(v1.z, v1.w);
        *reinterpret_cast<uint4*>(axk + (size_t)n * K2 + DIM + c8) = o;
    } else {                                   // ---- weights -> fragment order
        int id = (b - HB - CONVB) * 256 + threadIdx.x;   // 4096 total
        int l = id & 63, dt = (id >> 6) & 7, kk = id >> 9;
        int d = dt * 16 + (l & 15);
        int k = kk * 32 + (l >> 4) * 8;
        const float* src = (k < DIM) ? (Wl + (size_t)d * DIM + k)
                                     : (Wr + (size_t)d * DIM + (k - DIM));
        uint4 o;
        o.x = packbf(src[0], src[1]); o.y = packbf(src[2], src[3]);
        o.z = packbf(src[4], src[5]); o.w = packbf(src[6], src[7]);
        *reinterpret_cast<uint4*>(wb + (size_t)id * 8) = o;
    }
}

// ---------------------------------------------------------------------------
// CSR scan
// ---------------------------------------------------------------------------
__global__ __launch_bounds__(SCAN_B) void scan_block_kernel(
    const int* __restrict__ counts, int* __restrict__ incl, int* __restrict__ blksum)
{
    __shared__ int sh[SCAN_B];
    int t = threadIdx.x;
    int i = blockIdx.x * SCAN_B + t;
    sh[t] = (i < N_NODES) ? counts[i] : 0;
    __syncthreads();
    #pragma unroll
    for (int ofs = 1; ofs < SCAN_B; ofs <<= 1) {
        int add = (t >= ofs) ? sh[t - ofs] : 0;
        __syncthreads();
        sh[t] += add;
        __syncthreads();
    }
    if (i < N_NODES) incl[i] = sh[t];
    if (t == SCAN_B - 1) blksum[blockIdx.x] = sh[t];
}

__global__ __launch_bounds__(256) void scan_add_kernel(
    const int* __restrict__ counts, const int* __restrict__ incl,
    const int* __restrict__ blksum,
    int* __restrict__ row_start, int* __restrict__ wo, int E)
{
    __shared__ int soff;
    int b = blockIdx.x;
    if (threadIdx.x == 0) {
        int sb = (b * 256) >> 10;
        int run = 0;
        for (int j = 0; j < sb; ++j) run += blksum[j];
        soff = run;
    }
    __syncthreads();
    int i = b * 256 + threadIdx.x;
    if (i == 0) row_start[N_NODES] = E;
    if (i >= N_NODES) return;
    int excl = incl[i] + soff - counts[i];
    row_start[i] = excl;
    wo[i] = excl;
}

// ---------------------------------------------------------------------------
// XCD-sharded bucket fill (one XCD owns each shard's contiguous srcs window)
// ---------------------------------------------------------------------------
__global__ __launch_bounds__(256) void fill_kernel(
    const int* __restrict__ ei, int* __restrict__ wo, int* __restrict__ srcs, int E)
{
    int shard = blockIdx.x & (NSHARD - 1);
    int widx  = blockIdx.x >> 3;
    int lo = shard * SHROWS;
    int hi = min(lo + SHROWS, N_NODES);
    for (int e = widx * 256 + threadIdx.x; e < E; e += BPS * 256) {
        int dst = ei[E + e];
        int src = ei[e];
        if (dst >= lo && dst < hi) {
            int pos = atomicAdd(&wo[dst], 1);
            srcs[pos] = src;
        }
    }
}

// ---------------------------------------------------------------------------
// Aggregation: 32 lanes per node, 4-deep unrolled bf16 gather, fp32 accum,
// bf16 mean into axk[n][0:128]. No atomics.
// ---------------------------------------------------------------------------
__global__ __launch_bounds__(256) void aggregate_kernel(
    const int* __restrict__ srcs, const int* __restrict__ row_start,
    unsigned short* __restrict__ axk)
{
    int n = blockIdx.x * 8 + (threadIdx.x >> 5);
    if (n >= N_NODES) return;
    int lane = threadIdx.x & 31;
    int beg = row_start[n], end = row_start[n + 1];
    float a0 = 0.f, a1 = 0.f, a2 = 0.f, a3 = 0.f;
    const unsigned short* xb = axk + DIM + lane * 4;
    int e = beg;
    for (; e + 3 < end; e += 4) {                  // 4 gathers in flight
        int s0 = srcs[e], s1 = srcs[e + 1], s2 = srcs[e + 2], s3 = srcs[e + 3];
        ushort4 v0 = *reinterpret_cast<const ushort4*>(xb + (size_t)s0 * K2);
        ushort4 v1 = *reinterpret_cast<const ushort4*>(xb + (size_t)s1 * K2);
        ushort4 v2 = *reinterpret_cast<const ushort4*>(xb + (size_t)s2 * K2);
        ushort4 v3 = *reinterpret_cast<const ushort4*>(xb + (size_t)s3 * K2);
        a0 += (bf2f(v0.x) + bf2f(v1.x)) + (bf2f(v2.x) + bf2f(v3.x));
        a1 += (bf2f(v0.y) + bf2f(v1.y)) + (bf2f(v2.y) + bf2f(v3.y));
        a2 += (bf2f(v0.z) + bf2f(v1.z)) + (bf2f(v2.z) + bf2f(v3.z));
        a3 += (bf2f(v0.w) + bf2f(v1.w)) + (bf2f(v2.w) + bf2f(v3.w));
    }
    for (; e < end; ++e) {
        ushort4 v = *reinterpret_cast<const ushort4*>(xb + (size_t)srcs[e] * K2);
        a0 += bf2f(v.x); a1 += bf2f(v.y); a2 += bf2f(v.z); a3 += bf2f(v.w);
    }
    float inv = 1.0f / (float)max(end - beg, 1);
    ushort4 o;
    o.x = f2bf(a0 * inv); o.y = f2bf(a1 * inv);
    o.z = f2bf(a2 * inv); o.w = f2bf(a3 * inv);
    *reinterpret_cast<ushort4*>(axk + (size_t)n * K2 + lane * 4) = o;
}

// ---------------------------------------------------------------------------
// MFMA GEMM: preBN[n][d] = sum_k axk[n][k] * Wcat[d][k] + bl[d]
// 128 rows/block, 4 waves x 32 rows; per wave 2 row-tiles x 8 d-tiles,
// K=256 in 8 MFMA steps. B fragments read DIRECTLY from L2 (wb is 64KB,
// resident in every XCD L2; loads are fully coalesced) -- no LDS staging,
// so ~4 blocks/CU residency. Pre-BN stored bf16 over the consumed mean half
// of axk. Fused BN partials.
// ---------------------------------------------------------------------------
__global__ __launch_bounds__(256) void mfma_gemm_kernel(
    unsigned short* __restrict__ axk, const unsigned short* __restrict__ wb,
    const float* __restrict__ bl,
    float* __restrict__ ssum, float* __restrict__ ssq)
{
    __shared__ float sred[4][DIM];
    __shared__ float qred[4][DIM];

    const int t = threadIdx.x;
    const int wave = t >> 6, lane = t & 63;
    const int rowbase = blockIdx.x * GEMMROWS + wave * 32;
    const int lrow = lane & 15, lk = lane >> 4;

    f32x4 acc[2][8];
    #pragma unroll
    for (int rt = 0; rt < 2; ++rt)
        #pragma unroll
        for (int dt = 0; dt < 8; ++dt)
            acc[rt][dt] = (f32x4){0.f, 0.f, 0.f, 0.f};

    const unsigned short* abase = axk + (size_t)rowbase * K2 + lk * 8;
    const bf16x8* __restrict__ bfrag = reinterpret_cast<const bf16x8*>(wb) + lane;

    #pragma unroll
    for (int kk = 0; kk < 8; ++kk) {
        bf16x8 a[2];
        #pragma unroll
        for (int rt = 0; rt < 2; ++rt)
            a[rt] = *reinterpret_cast<const bf16x8*>(abase + (size_t)(rt * 16 + lrow) * K2 + kk * 32);
        #pragma unroll
        for (int dt = 0; dt < 8; ++dt) {
            bf16x8 b = bfrag[(kk * 8 + dt) * 64];     // coalesced, L2-hot
            #pragma unroll
            for (int rt = 0; rt < 2; ++rt)
                acc[rt][dt] = __builtin_amdgcn_mfma_f32_16x16x32_bf16(a[rt], b, acc[rt][dt], 0, 0, 0);
        }
    }

    // bias (part of BN input)
    #pragma unroll
    for (int dt = 0; dt < 8; ++dt) {
        float blv = bl[dt * 16 + lrow];
        #pragma unroll
        for (int rt = 0; rt < 2; ++rt)
            #pragma unroll
            for (int r = 0; r < 4; ++r) acc[rt][dt][r] += blv;
    }

    // store pre-BN as bf16 into the (consumed) mean half of axk
    #pragma unroll
    for (int rt = 0; rt < 2; ++rt)
        #pragma unroll
        for (int r = 0; r < 4; ++r) {
            int row = rowbase + rt * 16 + lk * 4 + r;
            if (row < N_NODES) {
                #pragma unroll
                for (int dt = 0; dt < 8; ++dt)
                    axk[(size_t)row * K2 + dt * 16 + lrow] = f2bf(acc[rt][dt][r]);
            }
        }

    // BN partial stats (fp32 accumulators, exact)
    #pragma unroll
    for (int dt = 0; dt < 8; ++dt) {
        float s = 0.f, q = 0.f;
        #pragma unroll
        for (int rt = 0; rt < 2; ++rt)
            #pragma unroll
            for (int r = 0; r < 4; ++r) {
                int row = rowbase + rt * 16 + lk * 4 + r;
                if (row < N_NODES) { float v = acc[rt][dt][r]; s += v; q = fmaf(v, v, q); }
            }
        s += __shfl_xor(s, 16); q += __shfl_xor(q, 16);
        s += __shfl_xor(s, 32); q += __shfl_xor(q, 32);
        if (lane < 16) { sred[wave][dt * 16 + lane] = s; qred[wave][dt * 16 + lane] = q; }
    }
    __syncthreads();
    if (t < DIM) {
        float s = sred[0][t] + sred[1][t] + sred[2][t] + sred[3][t];
        float q = qred[0][t] + qred[1][t] + qred[2][t] + qred[3][t];
        atomAddF(&ssum[t], s);
        atomAddF(&ssq[t], q);
    }
}

// ---------------------------------------------------------------------------
// Epilogue: BN (stats inlined) + ReLU + residual(bf16 x) -> fp32 out.
// One thread per 8 channels; reads one 512B axk row slice (preact+xb).
// ---------------------------------------------------------------------------
__global__ __launch_bounds__(256) void epilogue_kernel(
    const unsigned short* __restrict__ axk,
    const float* __restrict__ gamma, const float* __restrict__ beta,
    const float* __restrict__ ssum, const float* __restrict__ ssq,
    float* __restrict__ out)
{
    int i = blockIdx.x * 256 + threadIdx.x;   // one thread per 8 channels
    if (i >= N_NODES * 16) return;
    int n = i >> 4, c8 = (i & 15) << 3;
    const float invN = 1.0f / (float)N_NODES;

    ushort4 p0 = *reinterpret_cast<const ushort4*>(axk + (size_t)n * K2 + c8);
    ushort4 p1 = *reinterpret_cast<const ushort4*>(axk + (size_t)n * K2 + c8 + 4);
    ushort4 x0 = *reinterpret_cast<const ushort4*>(axk + (size_t)n * K2 + DIM + c8);
    ushort4 x1 = *reinterpret_cast<const ushort4*>(axk + (size_t)n * K2 + DIM + c8 + 4);

    float o[8];
    unsigned short pv[8] = {p0.x, p0.y, p0.z, p0.w, p1.x, p1.y, p1.z, p1.w};
    unsigned short xv[8] = {x0.x, x0.y, x0.z, x0.w, x1.x, x1.y, x1.z, x1.w};
    #pragma unroll
    for (int j = 0; j < 8; ++j) {
        int d = c8 + j;
        float m = ssum[d] * invN;
        float r = rsqrtf(fmaxf(ssq[d] * invN - m * m, 0.f) + 1e-5f);
        o[j] = fmaxf(gamma[d] * (bf2f(pv[j]) - m) * r + beta[d], 0.f) + bf2f(xv[j]);
    }
    float4 q0 = make_float4(o[0], o[1], o[2], o[3]);
    float4 q1 = make_float4(o[4], o[5], o[6], o[7]);
    *reinterpret_cast<float4*>(out + (size_t)n * DIM + c8) = q0;
    *reinterpret_cast<float4*>(out + (size_t)n * DIM + c8 + 4) = q1;
}

// ---------------------------------------------------------------------------
extern "C" void kernel_launch(void* const* d_in, const int* in_sizes, int n_in,
                              void* d_out, int out_size, void* d_ws, size_t ws_size,
                              hipStream_t stream)
{
    const float* x     = (const float*)d_in[0];
    const int*   ei    = (const int*)  d_in[1];
    const float* Wl    = (const float*)d_in[2];
    const float* bl    = (const float*)d_in[3];
    const float* Wr    = (const float*)d_in[4];
    const float* gamma = (const float*)d_in[5];
    const float* beta  = (const float*)d_in[6];
    float* out = (float*)d_out;

    const int E  = in_sizes[1] / 2;
    const int HB = (E + 255) / 256;

    // ws layout:
    // axk[NPAD*256] bf16 | wb[32768] bf16 | srcs[E] i32 | row_start[N+1] |
    // wo[N] | incl[N] | blksum[128] | counts[N] | ssum[D] | ssq[D]
    char* w = (char*)d_ws;
    unsigned short* axk = (unsigned short*)w;      w += (size_t)NPAD * K2 * 2;
    unsigned short* wb  = (unsigned short*)w;      w += (size_t)32768 * 2;
    int*   srcs      = (int*)w;                    w += (size_t)E * 4;
    int*   row_start = (int*)w;                    w += (size_t)(N_NODES + 1) * 4;
    int*   wo        = (int*)w;                    w += (size_t)N_NODES * 4;
    int*   incl      = (int*)w;                    w += (size_t)N_NODES * 4;
    int*   blksum    = (int*)w;                    w += 128 * 4;
    int*   counts    = (int*)w;                    w += (size_t)N_NODES * 4;
    float* ssum      = (float*)w;                  w += DIM * 4;
    float* ssq       = (float*)w;                  /* end */

    // zero counts + ssum + ssq (contiguous)
    hipMemsetAsync(counts, 0, ((size_t)N_NODES + 2 * DIM) * 4, stream);

    phase1_kernel<<<HB + CONVB + WBB, 256, 0, stream>>>(
        x, ei, Wl, Wr, axk, wb, counts, E, HB);
    scan_block_kernel<<<NSCANB, SCAN_B, 0, stream>>>(counts, incl, blksum);
    scan_add_kernel<<<(N_NODES + 255) / 256, 256, 0, stream>>>(
        counts, incl, blksum, row_start, wo, E);
    fill_kernel<<<NSHARD * BPS, 256, 0, stream>>>(ei, wo, srcs, E);

    aggregate_kernel<<<(N_NODES + 7) / 8, 256, 0, stream>>>(srcs, row_start, axk);

    mfma_gemm_kernel<<<NPAD / GEMMROWS, 256, 0, stream>>>(
        axk, wb, bl, ssum, ssq);

    epilogue_kernel<<<(N_NODES * 16 + 255) / 256, 256, 0, stream>>>(
        axk, gamma, beta, ssum, ssq, out);
}

// Round 9
// 267.898 us; speedup vs baseline: 1.0160x; 1.0160x over previous
//
#include <hip/hip_runtime.h>

#define N_NODES 100000
#define NPAD    100352          // padded row count for A (1568*64)
#define DIM     128
#define K2      256             // concatenated K ([preBN/mean | x])
#define SCAN_B  1024
#define NSCANB  ((N_NODES + SCAN_B - 1) / SCAN_B)   // 98
#define CONVB   6250            // convert blocks: N*16/256
#define WBB     16              // wb_build blocks
#define NSHARD  8
#define SHROWS  ((N_NODES + NSHARD - 1) / NSHARD)   // 12500
#define BPS     128             // fill blocks per shard
#define FROWS   64              // rows per fused block

typedef __attribute__((ext_vector_type(8))) short bf16x8;
typedef __attribute__((ext_vector_type(4))) float f32x4;

__device__ __forceinline__ void atomAddF(float* p, float v) { unsafeAtomicAdd(p, v); }

__device__ __forceinline__ float bf2f(unsigned short u) {
    union { unsigned u; float f; } c; c.u = ((unsigned)u) << 16; return c.f;
}
__device__ __forceinline__ unsigned short f2bf(float f) {
    union { float f; unsigned u; } c; c.f = f;
    unsigned r = (c.u + 0x7FFF + ((c.u >> 16) & 1)) >> 16;   // RNE
    return (unsigned short)r;
}
__device__ __forceinline__ unsigned packbf(float a, float b) {
    return (unsigned)f2bf(a) | ((unsigned)f2bf(b) << 16);
}
// accumulate 8 packed bf16 (uint4) into f[8]
__device__ __forceinline__ void accum8(float* f, uint4 v) {
    union { unsigned u; float fl; } c;
    c.u = v.x << 16;          f[0] += c.fl;
    c.u = v.x & 0xFFFF0000u;  f[1] += c.fl;
    c.u = v.y << 16;          f[2] += c.fl;
    c.u = v.y & 0xFFFF0000u;  f[3] += c.fl;
    c.u = v.z << 16;          f[4] += c.fl;
    c.u = v.z & 0xFFFF0000u;  f[5] += c.fl;
    c.u = v.w << 16;          f[6] += c.fl;
    c.u = v.w & 0xFFFF0000u;  f[7] += c.fl;
}

// ---------------------------------------------------------------------------
// Phase 1 (merged): hist(dst) | x->bf16 into axk[:,128:256] | W->bf16 frag order
// ---------------------------------------------------------------------------
__global__ __launch_bounds__(256) void phase1_kernel(
    const float* __restrict__ x, const int* __restrict__ ei,
    const float* __restrict__ Wl, const float* __restrict__ Wr,
    unsigned short* __restrict__ axk, unsigned short* __restrict__ wb,
    int* __restrict__ counts, int E, int HB)
{
    int b = blockIdx.x;
    if (b < HB) {                              // ---- histogram of dst
        int e = b * 256 + threadIdx.x;
        if (e < E) atomicAdd(&counts[ei[E + e]], 1);
    } else if (b < HB + CONVB) {               // ---- x -> bf16
        int i = (b - HB) * 256 + threadIdx.x;  // one thread per 8 floats
        int n = i >> 4, c8 = (i & 15) << 3;
        const float4* xp = reinterpret_cast<const float4*>(x + (size_t)n * DIM + c8);
        float4 v0 = xp[0], v1 = xp[1];
        uint4 o;
        o.x = packbf(v0.x, v0.y); o.y = packbf(v0.z, v0.w);
        o.z = packbf(v1.x, v1.y); o.w = packbf(v1.z, v1.w);
        *reinterpret_cast<uint4*>(axk + (size_t)n * K2 + DIM + c8) = o;
    } else {                                   // ---- weights -> fragment order
        int id = (b - HB - CONVB) * 256 + threadIdx.x;   // 4096 total
        int l = id & 63, dt = (id >> 6) & 7, kk = id >> 9;
        int d = dt * 16 + (l & 15);
        int k = kk * 32 + (l >> 4) * 8;
        const float* src = (k < DIM) ? (Wl + (size_t)d * DIM + k)
                                     : (Wr + (size_t)d * DIM + (k - DIM));
        uint4 o;
        o.x = packbf(src[0], src[1]); o.y = packbf(src[2], src[3]);
        o.z = packbf(src[4], src[5]); o.w = packbf(src[6], src[7]);
        *reinterpret_cast<uint4*>(wb + (size_t)id * 8) = o;
    }
}

// ---------------------------------------------------------------------------
// CSR scan
// ---------------------------------------------------------------------------
__global__ __launch_bounds__(SCAN_B) void scan_block_kernel(
    const int* __restrict__ counts, int* __restrict__ incl, int* __restrict__ blksum)
{
    __shared__ int sh[SCAN_B];
    int t = threadIdx.x;
    int i = blockIdx.x * SCAN_B + t;
    sh[t] = (i < N_NODES) ? counts[i] : 0;
    __syncthreads();
    #pragma unroll
    for (int ofs = 1; ofs < SCAN_B; ofs <<= 1) {
        int add = (t >= ofs) ? sh[t - ofs] : 0;
        __syncthreads();
        sh[t] += add;
        __syncthreads();
    }
    if (i < N_NODES) incl[i] = sh[t];
    if (t == SCAN_B - 1) blksum[blockIdx.x] = sh[t];
}

__global__ __launch_bounds__(256) void scan_add_kernel(
    const int* __restrict__ counts, const int* __restrict__ incl,
    const int* __restrict__ blksum,
    int* __restrict__ row_start, int* __restrict__ wo, int E)
{
    __shared__ int soff;
    int b = blockIdx.x;
    if (threadIdx.x == 0) {
        int sb = (b * 256) >> 10;
        int run = 0;
        for (int j = 0; j < sb; ++j) run += blksum[j];
        soff = run;
    }
    __syncthreads();
    int i = b * 256 + threadIdx.x;
    if (i == 0) row_start[N_NODES] = E;
    if (i >= N_NODES) return;
    int excl = incl[i] + soff - counts[i];
    row_start[i] = excl;
    wo[i] = excl;
}

// ---------------------------------------------------------------------------
// XCD-sharded bucket fill (one XCD owns each shard's contiguous srcs window)
// ---------------------------------------------------------------------------
__global__ __launch_bounds__(256) void fill_kernel(
    const int* __restrict__ ei, int* __restrict__ wo, int* __restrict__ srcs, int E)
{
    int shard = blockIdx.x & (NSHARD - 1);
    int widx  = blockIdx.x >> 3;
    int lo = shard * SHROWS;
    int hi = min(lo + SHROWS, N_NODES);
    for (int e = widx * 256 + threadIdx.x; e < E; e += BPS * 256) {
        int dst = ei[E + e];
        int src = ei[e];
        if (dst >= lo && dst < hi) {
            int pos = atomicAdd(&wo[dst], 1);
            srcs[pos] = src;
        }
    }
}

// ---------------------------------------------------------------------------
// Fused aggregate + MFMA GEMM + BN partials.
// Block = 256 threads, 64 rows.
// Phase A (gather): 16 groups x 16 lanes; group g, pass p owns tile row
//   tr = p*16+g (node rowbase+tr). Lane gl accumulates channels gl*8..+7 of
//   the neighbor xb rows in fp32, writes bf16 mean into swizzled LDS tile.
// Phase B (GEMM): 4 waves; wave w: row-tiles {2*(w>>1), 2*(w>>1)+1},
//   d-half w&1 (4 d-tiles). K=256: kk<4 mean-half from LDS, kk>=4 x-half
//   from global axk; B fragments from L2 (wb 64KB). preBN -> bf16 into the
//   consumed mean half of axk. Per-channel BN partials -> atomics.
// LDS swizzle: short col ^= (row&15)<<3 -> conflict-free writes and reads.
// ---------------------------------------------------------------------------
__global__ __launch_bounds__(256) void fused_agg_gemm_kernel(
    const int* __restrict__ srcs, const int* __restrict__ row_start,
    unsigned short* __restrict__ axk, const unsigned short* __restrict__ wb,
    const float* __restrict__ bl,
    float* __restrict__ ssum, float* __restrict__ ssq)
{
    __shared__ unsigned short Alds[FROWS][DIM];   // 16 KB
    __shared__ float sred[4][64];
    __shared__ float qred[4][64];

    const int t = threadIdx.x;
    const int rowbase = blockIdx.x * FROWS;

    // ---------------- Phase A: gather means ----------------
    {
        const int gid = t >> 4, gl = t & 15;
        const unsigned short* xb = axk + DIM + gl * 8;
        #pragma unroll
        for (int pass = 0; pass < 4; ++pass) {
            int tr = pass * 16 + gid;            // tr & 15 == gid
            int node = rowbase + tr;
            uint4 o = make_uint4(0u, 0u, 0u, 0u);
            if (node < N_NODES) {
                int beg = row_start[node], end = row_start[node + 1];
                float f[8] = {0.f, 0.f, 0.f, 0.f, 0.f, 0.f, 0.f, 0.f};
                int e = beg;
                for (; e + 3 < end; e += 4) {    // 4 gathers in flight
                    int s0 = srcs[e], s1 = srcs[e + 1], s2 = srcs[e + 2], s3 = srcs[e + 3];
                    uint4 v0 = *reinterpret_cast<const uint4*>(xb + (size_t)s0 * K2);
                    uint4 v1 = *reinterpret_cast<const uint4*>(xb + (size_t)s1 * K2);
                    uint4 v2 = *reinterpret_cast<const uint4*>(xb + (size_t)s2 * K2);
                    uint4 v3 = *reinterpret_cast<const uint4*>(xb + (size_t)s3 * K2);
                    accum8(f, v0); accum8(f, v1); accum8(f, v2); accum8(f, v3);
                }
                for (; e < end; ++e)
                    accum8(f, *reinterpret_cast<const uint4*>(xb + (size_t)srcs[e] * K2));
                float inv = 1.0f / (float)max(end - beg, 1);
                o.x = packbf(f[0] * inv, f[1] * inv);
                o.y = packbf(f[2] * inv, f[3] * inv);
                o.z = packbf(f[4] * inv, f[5] * inv);
                o.w = packbf(f[6] * inv, f[7] * inv);
            }
            *reinterpret_cast<uint4*>(&Alds[tr][(gl * 8) ^ (gid << 3)]) = o;
        }
    }
    __syncthreads();

    // ---------------- Phase B: MFMA GEMM ----------------
    const int wave = t >> 6, lane = t & 63;
    const int lrow = lane & 15, lk = lane >> 4;
    const int rt0 = (wave >> 1) * 2;      // row-tile pair base
    const int dh  = wave & 1;             // d-half

    f32x4 acc[2][4];
    #pragma unroll
    for (int rt = 0; rt < 2; ++rt)
        #pragma unroll
        for (int dt = 0; dt < 4; ++dt)
            acc[rt][dt] = (f32x4){0.f, 0.f, 0.f, 0.f};

    const bf16x8* __restrict__ bfrag = reinterpret_cast<const bf16x8*>(wb) + lane;

    #pragma unroll
    for (int kk = 0; kk < 8; ++kk) {
        bf16x8 a[2];
        if (kk < 4) {
            #pragma unroll
            for (int rt = 0; rt < 2; ++rt)
                a[rt] = *reinterpret_cast<const bf16x8*>(
                    &Alds[(rt0 + rt) * 16 + lrow][(kk * 32 + lk * 8) ^ (lrow << 3)]);
        } else {
            #pragma unroll
            for (int rt = 0; rt < 2; ++rt) {
                int row = rowbase + (rt0 + rt) * 16 + lrow;
                a[rt] = *reinterpret_cast<const bf16x8*>(
                    axk + (size_t)row * K2 + DIM + (kk - 4) * 32 + lk * 8);
            }
        }
        #pragma unroll
        for (int dt = 0; dt < 4; ++dt) {
            int dtg = dh * 4 + dt;
            bf16x8 b = bfrag[(kk * 8 + dtg) * 64];      // coalesced, L2-hot
            acc[0][dt] = __builtin_amdgcn_mfma_f32_16x16x32_bf16(a[0], b, acc[0][dt], 0, 0, 0);
            acc[1][dt] = __builtin_amdgcn_mfma_f32_16x16x32_bf16(a[1], b, acc[1][dt], 0, 0, 0);
        }
    }

    // bias (part of BN input)
    #pragma unroll
    for (int dt = 0; dt < 4; ++dt) {
        float blv = bl[dh * 64 + dt * 16 + lrow];
        #pragma unroll
        for (int rt = 0; rt < 2; ++rt)
            #pragma unroll
            for (int r = 0; r < 4; ++r) acc[rt][dt][r] += blv;
    }

    // store pre-BN bf16 into the (consumed) mean half of axk
    #pragma unroll
    for (int rt = 0; rt < 2; ++rt)
        #pragma unroll
        for (int r = 0; r < 4; ++r) {
            int row = rowbase + (rt0 + rt) * 16 + lk * 4 + r;
            if (row < N_NODES) {
                #pragma unroll
                for (int dt = 0; dt < 4; ++dt)
                    axk[(size_t)row * K2 + dh * 64 + dt * 16 + lrow] = f2bf(acc[rt][dt][r]);
            }
        }

    // BN partial stats (fp32, exact)
    #pragma unroll
    for (int dt = 0; dt < 4; ++dt) {
        float s = 0.f, q = 0.f;
        #pragma unroll
        for (int rt = 0; rt < 2; ++rt)
            #pragma unroll
            for (int r = 0; r < 4; ++r) {
                int row = rowbase + (rt0 + rt) * 16 + lk * 4 + r;
                if (row < N_NODES) { float v = acc[rt][dt][r]; s += v; q = fmaf(v, v, q); }
            }
        s += __shfl_xor(s, 16); q += __shfl_xor(q, 16);
        s += __shfl_xor(s, 32); q += __shfl_xor(q, 32);
        if (lane < 16) { sred[wave][dt * 16 + lane] = s; qred[wave][dt * 16 + lane] = q; }
    }
    __syncthreads();
    if (t < DIM) {
        int c = t & 63, h = t >> 6;           // chans 0..63 from waves 0,2; 64..127 from 1,3
        float s = sred[h][c] + sred[h + 2][c];
        float q = qred[h][c] + qred[h + 2][c];
        atomAddF(&ssum[t], s);
        atomAddF(&ssq[t], q);
    }
}

// ---------------------------------------------------------------------------
// Epilogue: BN (stats inlined) + ReLU + residual(bf16 x) -> fp32 out.
// ---------------------------------------------------------------------------
__global__ __launch_bounds__(256) void epilogue_kernel(
    const unsigned short* __restrict__ axk,
    const float* __restrict__ gamma, const float* __restrict__ beta,
    const float* __restrict__ ssum, const float* __restrict__ ssq,
    float* __restrict__ out)
{
    int i = blockIdx.x * 256 + threadIdx.x;   // one thread per 8 channels
    if (i >= N_NODES * 16) return;
    int n = i >> 4, c8 = (i & 15) << 3;
    const float invN = 1.0f / (float)N_NODES;

    ushort4 p0 = *reinterpret_cast<const ushort4*>(axk + (size_t)n * K2 + c8);
    ushort4 p1 = *reinterpret_cast<const ushort4*>(axk + (size_t)n * K2 + c8 + 4);
    ushort4 x0 = *reinterpret_cast<const ushort4*>(axk + (size_t)n * K2 + DIM + c8);
    ushort4 x1 = *reinterpret_cast<const ushort4*>(axk + (size_t)n * K2 + DIM + c8 + 4);

    float o[8];
    unsigned short pv[8] = {p0.x, p0.y, p0.z, p0.w, p1.x, p1.y, p1.z, p1.w};
    unsigned short xv[8] = {x0.x, x0.y, x0.z, x0.w, x1.x, x1.y, x1.z, x1.w};
    #pragma unroll
    for (int j = 0; j < 8; ++j) {
        int d = c8 + j;
        float m = ssum[d] * invN;
        float r = rsqrtf(fmaxf(ssq[d] * invN - m * m, 0.f) + 1e-5f);
        o[j] = fmaxf(gamma[d] * (bf2f(pv[j]) - m) * r + beta[d], 0.f) + bf2f(xv[j]);
    }
    float4 q0 = make_float4(o[0], o[1], o[2], o[3]);
    float4 q1 = make_float4(o[4], o[5], o[6], o[7]);
    *reinterpret_cast<float4*>(out + (size_t)n * DIM + c8) = q0;
    *reinterpret_cast<float4*>(out + (size_t)n * DIM + c8 + 4) = q1;
}

// ---------------------------------------------------------------------------
extern "C" void kernel_launch(void* const* d_in, const int* in_sizes, int n_in,
                              void* d_out, int out_size, void* d_ws, size_t ws_size,
                              hipStream_t stream)
{
    const float* x     = (const float*)d_in[0];
    const int*   ei    = (const int*)  d_in[1];
    const float* Wl    = (const float*)d_in[2];
    const float* bl    = (const float*)d_in[3];
    const float* Wr    = (const float*)d_in[4];
    const float* gamma = (const float*)d_in[5];
    const float* beta  = (const float*)d_in[6];
    float* out = (float*)d_out;

    const int E  = in_sizes[1] / 2;
    const int HB = (E + 255) / 256;

    // ws layout:
    // axk[NPAD*256] bf16 | wb[32768] bf16 | srcs[E] i32 | row_start[N+1] |
    // wo[N] | incl[N] | blksum[128] | counts[N] | ssum[D] | ssq[D]
    char* w = (char*)d_ws;
    unsigned short* axk = (unsigned short*)w;      w += (size_t)NPAD * K2 * 2;
    unsigned short* wb  = (unsigned short*)w;      w += (size_t)32768 * 2;
    int*   srcs      = (int*)w;                    w += (size_t)E * 4;
    int*   row_start = (int*)w;                    w += (size_t)(N_NODES + 1) * 4;
    int*   wo        = (int*)w;                    w += (size_t)N_NODES * 4;
    int*   incl      = (int*)w;                    w += (size_t)N_NODES * 4;
    int*   blksum    = (int*)w;                    w += 128 * 4;
    int*   counts    = (int*)w;                    w += (size_t)N_NODES * 4;
    float* ssum      = (float*)w;                  w += DIM * 4;
    float* ssq       = (float*)w;                  /* end */

    // zero counts + ssum + ssq (contiguous)
    hipMemsetAsync(counts, 0, ((size_t)N_NODES + 2 * DIM) * 4, stream);

    phase1_kernel<<<HB + CONVB + WBB, 256, 0, stream>>>(
        x, ei, Wl, Wr, axk, wb, counts, E, HB);
    scan_block_kernel<<<NSCANB, SCAN_B, 0, stream>>>(counts, incl, blksum);
    scan_add_kernel<<<(N_NODES + 255) / 256, 256, 0, stream>>>(
        counts, incl, blksum, row_start, wo, E);
    fill_kernel<<<NSHARD * BPS, 256, 0, stream>>>(ei, wo, srcs, E);

    fused_agg_gemm_kernel<<<NPAD / FROWS, 256, 0, stream>>>(
        srcs, row_start, axk, wb, bl, ssum, ssq);

    epilogue_kernel<<<(N_NODES * 16 + 255) / 256, 256, 0, stream>>>(
        axk, gamma, beta, ssum, ssq, out);
}